// Round 1
// baseline (163.696 us; speedup 1.0000x reference)
//
#include <hip/hip_runtime.h>
#include <math.h>

// Problem constants
#define B_   128
#define IN_  1024
#define OUT_ 1024
#define E_   32
#define K_   2

// moe_main tiling
#define CHUNK 16     // samples per block
#define ISEG  128    // inner-dim segment per block
#define NSEG  (IN_ / ISEG)   // 8
#define MAXCH (B_ / CHUNK)   // 8 (max possible samples per expert = 128)

// ---------------- Kernel A: routing (both routers), top-2 + softmax ----------------
// route layout per sample b (8 floats): [i0, i1, p0, p1, ib0, ib1, pb0, pb1]
// (indices bit-cast to float)
__global__ __launch_bounds__(256) void route_kernel(
    const float* __restrict__ x, const float* __restrict__ rw,
    const float* __restrict__ brw, float* __restrict__ route) {
  int b = blockIdx.x;
  int t = threadIdx.x;
  __shared__ float xs[IN_];
  __shared__ float part[256];
  __shared__ float lg[64];

  // stage x[b] into LDS (256 threads * float4)
  ((float4*)xs)[t] = ((const float4*)(x + (size_t)b * IN_))[t];
  __syncthreads();

  // 64 (router,e) pairs, 4 partial threads each
  int er = t & 63;          // 0..31 main router, 32..63 bias router
  int q  = t >> 6;          // 0..3 -> i quarter
  int e  = er & 31;
  const float* w = (er < 32) ? rw : brw;
  float acc = 0.f;
  int i0 = q * 256;
  for (int i = i0; i < i0 + 256; ++i)
    acc += xs[i] * w[(size_t)i * E_ + e];
  part[t] = acc;
  __syncthreads();
  if (t < 64) lg[t] = part[t] + part[t + 64] + part[t + 128] + part[t + 192];
  __syncthreads();

  if (t < 2) {
    const float* l = lg + t * 32;
    int bi0 = -1, bi1 = -1;
    float v0 = -INFINITY, v1 = -INFINITY;
    for (int ee = 0; ee < E_; ++ee) {
      float v = l[ee];
      if (v > v0) { v1 = v0; bi1 = bi0; v0 = v; bi0 = ee; }
      else if (v > v1) { v1 = v; bi1 = ee; }
    }
    // softmax over {v0, v1}, v0 >= v1
    float p0 = 1.f / (1.f + expf(v1 - v0));
    float p1 = 1.f - p0;
    float* r = route + (size_t)b * 8 + t * 4;
    r[0] = __int_as_float(bi0);
    r[1] = __int_as_float(bi1);
    r[2] = p0;
    r[3] = p1;
  }
}

// ---------------- Kernel A2: build per-expert sample lists (deterministic) ----------------
__global__ void build_lists(const float* __restrict__ route,
                            int* __restrict__ counts,
                            int* __restrict__ list_b,
                            float* __restrict__ list_p) {
  int t = threadIdx.x;   // 32 threads, one per expert
  if (t >= E_) return;
  int c = 0;
  for (int b = 0; b < B_; ++b) {
    const float* r = route + (size_t)b * 8;
    int i0 = __float_as_int(r[0]);
    int i1 = __float_as_int(r[1]);
    if (i0 == t)      { list_b[t * B_ + c] = b; list_p[t * B_ + c] = r[2]; ++c; }
    else if (i1 == t) { list_b[t * B_ + c] = b; list_p[t * B_ + c] = r[3]; ++c; }
  }
  counts[t] = c;
}

// ---------------- Kernel B: out = mix_b @ expert_biases ----------------
__global__ __launch_bounds__(256) void bias_init(
    const float* __restrict__ route, const float* __restrict__ eb,
    float* __restrict__ out) {
  int b = blockIdx.x;
  int t = threadIdx.x;
  const float* r = route + (size_t)b * 8 + 4;
  int i0 = __float_as_int(r[0]);
  int i1 = __float_as_int(r[1]);
  float p0 = r[2], p1 = r[3];
  float4 b0 = ((const float4*)(eb + (size_t)i0 * OUT_))[t];
  float4 b1 = ((const float4*)(eb + (size_t)i1 * OUT_))[t];
  float4 o;
  o.x = p0 * b0.x + p1 * b1.x;
  o.y = p0 * b0.y + p1 * b1.y;
  o.z = p0 * b0.z + p1 * b1.z;
  o.w = p0 * b0.w + p1 * b1.w;
  ((float4*)(out + (size_t)b * OUT_))[t] = o;
}

// ---------------- Kernel C: grouped expert matvecs, atomic accumulate ----------------
__global__ __launch_bounds__(256) void moe_main(
    const float* __restrict__ x, const float* __restrict__ ew,
    const int* __restrict__ counts, const int* __restrict__ list_b,
    const float* __restrict__ list_p, float* __restrict__ out) {
  int e    = blockIdx.x;       // expert
  int iseg = blockIdx.y;       // i segment (128 wide)
  int ch   = blockIdx.z;       // sample chunk
  int c = counts[e];
  int s0 = ch * CHUNK;
  if (s0 >= c) return;
  int ns = min(CHUNK, c - s0);

  __shared__ float xs[CHUNK][ISEG];
  __shared__ int   bs[CHUNK];
  __shared__ float ps[CHUNK];
  int t = threadIdx.x;   // 256

  if (t < CHUNK) {
    int idx = (t < ns) ? (s0 + t) : s0;   // clamp to a valid sample
    bs[t] = list_b[e * B_ + idx];
    ps[t] = (t < ns) ? list_p[e * B_ + idx] : 0.f;
  }
  __syncthreads();

  // stage x segments: CHUNK*ISEG = 2048 floats = 512 float4; 256 thr * 2
  {
    int ibase = iseg * ISEG;
    #pragma unroll
    for (int k = 0; k < 2; ++k) {
      int idx = t + k * 256;            // float4 index in [0,512)
      int s = idx >> 5;                 // 32 float4 per row
      int c4 = idx & 31;
      ((float4*)xs[s])[c4] =
          ((const float4*)(x + (size_t)bs[s] * IN_ + ibase))[c4];
    }
  }
  __syncthreads();

  // each thread owns 4 consecutive outputs: o = 4t .. 4t+3
  const float* wp = ew + ((size_t)e * IN_ + (size_t)iseg * ISEG) * OUT_ + 4 * t;
  float4 acc[CHUNK];
  #pragma unroll
  for (int s = 0; s < CHUNK; ++s) acc[s] = make_float4(0.f, 0.f, 0.f, 0.f);

  for (int i = 0; i < ISEG; ++i) {
    float4 w4 = *(const float4*)(wp + (size_t)i * OUT_);
    #pragma unroll
    for (int s = 0; s < CHUNK; ++s) {
      float f = xs[s][i];
      acc[s].x += f * w4.x;
      acc[s].y += f * w4.y;
      acc[s].z += f * w4.z;
      acc[s].w += f * w4.w;
    }
  }

  for (int s = 0; s < ns; ++s) {
    float p = ps[s];
    float* op = out + (size_t)bs[s] * OUT_ + 4 * t;
    atomicAdd(op + 0, p * acc[s].x);
    atomicAdd(op + 1, p * acc[s].y);
    atomicAdd(op + 2, p * acc[s].z);
    atomicAdd(op + 3, p * acc[s].w);
  }
}

extern "C" void kernel_launch(void* const* d_in, const int* in_sizes, int n_in,
                              void* d_out, int out_size, void* d_ws, size_t ws_size,
                              hipStream_t stream) {
  const float* x   = (const float*)d_in[0];
  const float* rw  = (const float*)d_in[1];
  const float* brw = (const float*)d_in[2];
  const float* ew  = (const float*)d_in[3];
  const float* eb  = (const float*)d_in[4];
  float* out = (float*)d_out;

  // workspace layout
  float* route  = (float*)d_ws;                                   // 128*8 floats = 4 KB
  int*   counts = (int*)((char*)d_ws + 4096);                     // 32 ints
  int*   list_b = (int*)((char*)d_ws + 4096 + 128);               // 32*128 ints
  float* list_p = (float*)((char*)d_ws + 4096 + 128 + 16384);     // 32*128 floats

  route_kernel<<<B_, 256, 0, stream>>>(x, rw, brw, route);
  build_lists<<<1, 32, 0, stream>>>(route, counts, list_b, list_p);
  bias_init<<<B_, 256, 0, stream>>>(route, eb, out);
  moe_main<<<dim3(E_, NSEG, MAXCH), 256, 0, stream>>>(x, ew, counts, list_b, list_p, out);
}

// Round 2
// 153.448 us; speedup vs baseline: 1.0668x; 1.0668x over previous
//
#include <hip/hip_runtime.h>
#include <math.h>

// Problem constants
#define B_   128
#define IN_  1024
#define OUT_ 1024
#define E_   32
#define K_   2

// moe_main tiling: block = (expert, output-segment, sample-chunk)
#define CHUNK 16             // samples per block (2 per wave, 8 waves)
#define OSEG  128            // output columns per block (2 per lane)
#define NOSEG (OUT_ / OSEG)  // 8
#define MAXCH (B_ / CHUNK)   // 8
#define IT    256            // i-tile staged in LDS
#define NIT   (IN_ / IT)     // 4

// ---------------- Kernel A: routing (both routers) + top-2 softmax + bias init ----
// route layout per sample b (8 floats): [i0, i1, p0, p1, ib0, ib1, pb0, pb1]
__global__ __launch_bounds__(256) void route_fused(
    const float* __restrict__ x, const float* __restrict__ rw,
    const float* __restrict__ brw, const float* __restrict__ eb,
    float* __restrict__ route, float* __restrict__ out) {
  int b = blockIdx.x;
  int t = threadIdx.x;
  __shared__ float xs[IN_];
  __shared__ float part[256];
  __shared__ float lg[64];
  __shared__ float res[8];

  ((float4*)xs)[t] = ((const float4*)(x + (size_t)b * IN_))[t];
  __syncthreads();

  // 64 (router,e) pairs, 4 partial threads each
  int er = t & 63;
  int q  = t >> 6;
  int e  = er & 31;
  const float* w = (er < 32) ? rw : brw;
  float acc = 0.f;
  int i0 = q * 256;
  for (int i = i0; i < i0 + 256; ++i)
    acc += xs[i] * w[(size_t)i * E_ + e];
  part[t] = acc;
  __syncthreads();
  if (t < 64) lg[t] = part[t] + part[t + 64] + part[t + 128] + part[t + 192];
  __syncthreads();

  if (t < 2) {
    const float* l = lg + t * 32;
    int bi0 = -1, bi1 = -1;
    float v0 = -INFINITY, v1 = -INFINITY;
    for (int ee = 0; ee < E_; ++ee) {
      float v = l[ee];
      if (v > v0) { v1 = v0; bi1 = bi0; v0 = v; bi0 = ee; }
      else if (v > v1) { v1 = v; bi1 = ee; }
    }
    float p0 = 1.f / (1.f + expf(v1 - v0));
    float p1 = 1.f - p0;
    float* r = route + (size_t)b * 8 + t * 4;
    r[0] = __int_as_float(bi0);
    r[1] = __int_as_float(bi1);
    r[2] = p0;
    r[3] = p1;
    res[t * 4 + 0] = __int_as_float(bi0);
    res[t * 4 + 1] = __int_as_float(bi1);
    res[t * 4 + 2] = p0;
    res[t * 4 + 3] = p1;
  }
  __syncthreads();

  // bias init: out[b] = pb0*eb[ib0] + pb1*eb[ib1]
  int ib0 = __float_as_int(res[4]);
  int ib1 = __float_as_int(res[5]);
  float pb0 = res[6], pb1 = res[7];
  float4 b0 = ((const float4*)(eb + (size_t)ib0 * OUT_))[t];
  float4 b1 = ((const float4*)(eb + (size_t)ib1 * OUT_))[t];
  float4 o;
  o.x = pb0 * b0.x + pb1 * b1.x;
  o.y = pb0 * b0.y + pb1 * b1.y;
  o.z = pb0 * b0.z + pb1 * b1.z;
  o.w = pb0 * b0.w + pb1 * b1.w;
  ((float4*)(out + (size_t)b * OUT_))[t] = o;
}

// ---------------- Kernel A2: per-expert sample lists (LDS-staged, deterministic) ----
__global__ __launch_bounds__(128) void build_lists(
    const float* __restrict__ route, int* __restrict__ counts,
    int* __restrict__ list_b, float* __restrict__ list_p) {
  __shared__ float4 r_sh[B_];
  int t = threadIdx.x;  // 128
  r_sh[t] = *(const float4*)(route + (size_t)t * 8);  // [i0,i1,p0,p1]
  __syncthreads();
  if (t < E_) {
    int c = 0;
    for (int b = 0; b < B_; ++b) {
      float4 r = r_sh[b];
      int i0 = __float_as_int(r.x);
      int i1 = __float_as_int(r.y);
      if (i0 == t)      { list_b[t * B_ + c] = b; list_p[t * B_ + c] = r.z; ++c; }
      else if (i1 == t) { list_b[t * B_ + c] = b; list_p[t * B_ + c] = r.w; ++c; }
    }
    counts[t] = c;
  }
}

// ---------------- Kernel B: grouped expert matvecs, full-K per block ----------------
// block = (e, oseg, chunk); 512 threads = 8 waves; wave w handles samples 2w, 2w+1;
// lane owns output cols oseg*128 + lane*2 .. +1. acc is fully static-indexed.
__global__ __launch_bounds__(512) void moe_main(
    const float* __restrict__ x, const float* __restrict__ ew,
    const int* __restrict__ counts, const int* __restrict__ list_b,
    const float* __restrict__ list_p, float* __restrict__ out) {
  int e    = blockIdx.x;
  int oseg = blockIdx.y;
  int ch   = blockIdx.z;
  int c = counts[e];
  int s0 = ch * CHUNK;
  if (s0 >= c) return;
  int ns = min(CHUNK, c - s0);

  __shared__ float xs[CHUNK][IT + 4];   // row stride 260 floats (1040 B, 16B-aligned)
  __shared__ int   bs[CHUNK];
  __shared__ float ps[CHUNK];

  int t = threadIdx.x;
  int lane = t & 63;
  int w    = t >> 6;      // wave id 0..7

  if (t < CHUNK) {
    int idx = s0 + min(t, ns - 1);      // clamp padding to a valid sample row
    bs[t] = list_b[e * B_ + idx];
    ps[t] = (t < ns) ? list_p[e * B_ + idx] : 0.f;
  }
  __syncthreads();

  bool active = (2 * w < ns);
  float2 a0 = make_float2(0.f, 0.f);
  float2 a1 = make_float2(0.f, 0.f);

  const float* wcol = ew + (size_t)e * IN_ * OUT_ + (size_t)oseg * OSEG + lane * 2;

  for (int it = 0; it < NIT; ++it) {
    // stage x tile: CHUNK rows x IT floats = 1024 float4; 512 threads x 2
    #pragma unroll
    for (int k = 0; k < 2; ++k) {
      int idx = t + k * 512;            // 0..1023
      int s   = idx >> 6;               // wave-uniform row
      int c4  = idx & 63;
      ((float4*)xs[s])[c4] =
          ((const float4*)(x + (size_t)bs[s] * IN_ + it * IT))[c4];
    }
    __syncthreads();

    if (active) {
      const float* wr = wcol + (size_t)(it * IT) * OUT_;
      const float* x0 = xs[2 * w];
      const float* x1 = xs[2 * w + 1];
      #pragma unroll 16
      for (int i = 0; i < IT; ++i) {
        float2 w2 = *(const float2*)(wr + (size_t)i * OUT_);
        float f0 = x0[i];
        float f1 = x1[i];
        a0.x += f0 * w2.x; a0.y += f0 * w2.y;
        a1.x += f1 * w2.x; a1.y += f1 * w2.y;
      }
    }
    __syncthreads();
  }

  // epilogue: static indexing only
  int s_0 = 2 * w;
  if (s_0 < ns) {
    float p = ps[s_0];
    float* op = out + (size_t)bs[s_0] * OUT_ + (size_t)oseg * OSEG + lane * 2;
    atomicAdd(op + 0, p * a0.x);
    atomicAdd(op + 1, p * a0.y);
  }
  int s_1 = 2 * w + 1;
  if (s_1 < ns) {
    float p = ps[s_1];
    float* op = out + (size_t)bs[s_1] * OUT_ + (size_t)oseg * OSEG + lane * 2;
    atomicAdd(op + 0, p * a1.x);
    atomicAdd(op + 1, p * a1.y);
  }
}

extern "C" void kernel_launch(void* const* d_in, const int* in_sizes, int n_in,
                              void* d_out, int out_size, void* d_ws, size_t ws_size,
                              hipStream_t stream) {
  const float* x   = (const float*)d_in[0];
  const float* rw  = (const float*)d_in[1];
  const float* brw = (const float*)d_in[2];
  const float* ew  = (const float*)d_in[3];
  const float* eb  = (const float*)d_in[4];
  float* out = (float*)d_out;

  float* route  = (float*)d_ws;                                   // 128*8 floats = 4 KB
  int*   counts = (int*)((char*)d_ws + 4096);                     // 32 ints
  int*   list_b = (int*)((char*)d_ws + 4096 + 128);               // 32*128 ints
  float* list_p = (float*)((char*)d_ws + 4096 + 128 + 16384);     // 32*128 floats

  route_fused<<<B_, 256, 0, stream>>>(x, rw, brw, eb, route, out);
  build_lists<<<1, 128, 0, stream>>>(route, counts, list_b, list_p);
  moe_main<<<dim3(E_, NOSEG, MAXCH), 512, 0, stream>>>(x, ew, counts, list_b, list_p, out);
}